// Round 21
// baseline (93.169 us; speedup 1.0000x reference)
//
#include <hip/hip_runtime.h>
#include <hip/hip_cooperative_groups.h>
#include <hip/hip_fp16.h>
#include <stdint.h>

namespace cg = cooperative_groups;

#define TOKENS 2048
#define DIM    2048
#define GROUP  128
#define NGK    16   // K-groups per row

typedef __attribute__((ext_vector_type(4)))  int   i32x4;
typedef __attribute__((ext_vector_type(4)))  float f32x4;

// nearest merged-grid point in q/4 units: ints {-7..7} U +-{12,16,24,32,48,64,96}
__device__ __forceinline__ float nearest_q4(float u) {
  float qi = fminf(fmaxf(rintf(u), -7.f), 7.f);
  float a = fabsf(u);
  float m = a <= 14.f ? 12.f : a <= 20.f ? 16.f : a <= 28.f ? 24.f
          : a <= 40.f ? 32.f : a <= 56.f ? 48.f : a <= 80.f ? 64.f : 96.f;
  float qo = copysignf(m, u);
  return (fabsf(u - qo) < fabsf(u - qi)) ? qo : qi;   // int grid wins ties
}

__device__ __forceinline__ void gload_lds16(const int8_t* g, char* l) {
  __builtin_amdgcn_global_load_lds(
      (__attribute__((address_space(1))) uint32_t*)g,
      (__attribute__((address_space(3))) uint32_t*)l, 16, 0, 0);
}

// one wave-pair quant step (R15 code): quantize group g from src
__device__ __forceinline__ void quant_group(
    int g, const float* __restrict__ x, const float* __restrict__ w,
    int8_t* __restrict__ q8, float* __restrict__ ssxT,
    float* __restrict__ sswT, int l) {
  const int NG1 = TOKENS * DIM / GROUP;   // 32768
  const float alpha = (g < NG1) ? 0.9f : 1.0f;
  const float* src  = (g < NG1) ? x : w;
  const int grow    = (g < NG1) ? g : g - NG1;
  const size_t sbase = (size_t)grow * GROUP + l * 4;

  const float4 v = *reinterpret_cast<const float4*>(src + sbase);

  float s  = (v.x + v.y) + (v.z + v.w);
  float ss = fmaf(v.x, v.x, fmaf(v.y, v.y, fmaf(v.z, v.z, v.w * v.w)));
#pragma unroll
  for (int off = 16; off > 0; off >>= 1) {
    s  += __shfl_xor(s,  off, 64);
    ss += __shfl_xor(ss, off, 64);
  }
  const float mean = s * (1.0f / 128.0f);
  const float var  = fmaf(-mean, s, ss) * (1.0f / 127.0f);
  const float scale = fmaf(3.0f, sqrtf(var), fabsf(mean)) * (alpha / 28.0f);
  const float rs4 = 0.25f / scale;

  const float u0 = v.x * rs4, u1 = v.y * rs4, u2 = v.z * rs4, u3 = v.w * rs4;
  const float amax = fmaxf(fmaxf(fabsf(u0), fabsf(u1)),
                           fmaxf(fabsf(u2), fabsf(u3)));

  int i0, i1, i2, i3;
  if (__any(amax >= 9.5f)) {
    float q0 = nearest_q4(u0);
    float q1 = nearest_q4(u1);
    float q2 = nearest_q4(u2);
    float q3 = nearest_q4(u3);
    if (fabsf(q0) > 8.0f)      q1 = 0.0f;
    else if (fabsf(q1) > 8.0f) q0 = 0.0f;
    if (fabsf(q2) > 8.0f)      q3 = 0.0f;
    else if (fabsf(q3) > 8.0f) q2 = 0.0f;
    i0 = (int)q0; i1 = (int)q1; i2 = (int)q2; i3 = (int)q3;
  } else {
    i0 = (int)fminf(fmaxf(rintf(u0), -7.f), 7.f);
    i1 = (int)fminf(fmaxf(rintf(u1), -7.f), 7.f);
    i2 = (int)fminf(fmaxf(rintf(u2), -7.f), 7.f);
    i3 = (int)fminf(fmaxf(rintf(u3), -7.f), 7.f);
  }

  const int p = (i0 & 255) | ((i1 & 255) << 8) |
                ((i2 & 255) << 16) | ((i3 & 255) << 24);
  reinterpret_cast<int*>(q8)[(size_t)g * 32 + l] = p;

  if (l == 0) {
    const float ssc = 4.0f * scale;
    if (g < NG1) ssxT[(grow & 15) * 2048 + (grow >> 4)] = ssc;
    else         sswT[(grow & 15) * 2048 + (grow >> 4)] = ssc;
  }
}

// ---------------- standalone kernels (fallback path = exact R17) ------------

__global__ __launch_bounds__(256) void quant2_kernel(
    const float* __restrict__ x, const float* __restrict__ w,
    int8_t* __restrict__ q8, float* __restrict__ ssxT,
    float* __restrict__ sswT) {
  const int wid  = threadIdx.x >> 6;
  const int lane = threadIdx.x & 63;
  const int g    = blockIdx.x * 8 + wid * 2 + (lane >> 5);
  quant_group(g, x, w, q8, ssxT, sswT, lane & 31);
}

// GEMM tile body shared by standalone + fused (R17 proven code)
template <typename LDS>
__device__ __forceinline__ void gemm_tile(
    int bid, const int8_t* __restrict__ Aq, const int8_t* __restrict__ Bq,
    const float* __restrict__ ssxT, const float* __restrict__ sswT,
    float* __restrict__ C, LDS* lds_raw_v, int tid) {
  char* lds_raw = (char*)lds_raw_v;
  float* ssx_l = (float*)(lds_raw + 32768);          // [16][64]
  float* ssw_l = (float*)(lds_raw + 32768 + 4096);   // [16][64]

  const int lane = tid & 63;
  const int wid  = tid >> 6;
  const int wr   = wid >> 1;
  const int wc   = wid & 1;
  const int r15  = lane & 15;
  const int hi4  = lane >> 4;

  // XCD c owns bm in [(c&3)*8,+8), bn in [(c>>2)*16,+16)
  const int c   = bid & 7;
  const int idx = bid >> 3;
  const int bm  = ((c & 3) << 3) + (idx >> 4);
  const int bn  = ((c >> 2) << 4) + (idx & 15);

  const int8_t* gA = Aq + (size_t)(bm * 64) * DIM;
  const int8_t* gB = Bq + (size_t)(bn * 64) * DIM;

  auto stage = [&](char* buf, int g) {
#pragma unroll
    for (int i = 0; i < 2; ++i) {     // A: 64x128 i8 = 8 KB
      int P   = (i * 256 + tid) * 16;
      int row = P >> 7;
      int cb  = (P & 127) ^ ((row & 7) << 4);
      gload_lds16(gA + (size_t)row * DIM + g * 128 + cb, buf + P);
    }
#pragma unroll
    for (int i = 0; i < 2; ++i) {     // B: 64x128 i8 = 8 KB
      int P   = (i * 256 + tid) * 16;
      int row = P >> 7;
      int cb  = (P & 127) ^ ((row & 7) << 4);
      gload_lds16(gB + (size_t)row * DIM + g * 128 + cb, buf + 8192 + P);
    }
  };

  {                                   // ssx: 1024 floats
    int f = tid * 4;
    *reinterpret_cast<f32x4*>(&ssx_l[f]) =
        *reinterpret_cast<const f32x4*>(&ssxT[(f >> 6) * 2048 + bm * 64 + (f & 63)]);
  }
  {                                   // ssw: 1024 floats
    int f = tid * 4;
    *reinterpret_cast<f32x4*>(&ssw_l[f]) =
        *reinterpret_cast<const f32x4*>(&sswT[(f >> 6) * 2048 + bn * 64 + (f & 63)]);
  }

  f32x4 accf[2][2] = {};
  const i32x4 zacc = {};

  auto compute = [&](const char* buf, int gk) {
    const char* cA = buf;
    const char* cB = buf + 8192;
    i32x4 acci[2][2];
#pragma unroll
    for (int kh = 0; kh < 2; ++kh) {
      const int kb = kh * 64 + hi4 * 16;
      i32x4 af[2], bf[2];
#pragma unroll
      for (int mt = 0; mt < 2; ++mt) {
        int row = wr * 32 + mt * 16 + r15;
        int pc  = kb ^ ((row & 7) << 4);
        af[mt] = *reinterpret_cast<const i32x4*>(cA + (row << 7) + pc);
      }
#pragma unroll
      for (int nt = 0; nt < 2; ++nt) {
        int row = wc * 32 + nt * 16 + r15;
        int pc  = kb ^ ((row & 7) << 4);
        bf[nt] = *reinterpret_cast<const i32x4*>(cB + (row << 7) + pc);
      }
      __builtin_amdgcn_s_setprio(1);
#pragma unroll
      for (int mt = 0; mt < 2; ++mt)
#pragma unroll
        for (int nt = 0; nt < 2; ++nt)
          acci[mt][nt] = __builtin_amdgcn_mfma_i32_16x16x64_i8(
              af[mt], bf[nt], kh == 0 ? zacc : acci[mt][nt], 0, 0, 0);
      __builtin_amdgcn_s_setprio(0);
    }
    float sw[2];
#pragma unroll
    for (int nt = 0; nt < 2; ++nt)
      sw[nt] = ssw_l[gk * 64 + wc * 32 + nt * 16 + r15];
#pragma unroll
    for (int mt = 0; mt < 2; ++mt) {
      f32x4 sx = *reinterpret_cast<const f32x4*>(
          &ssx_l[gk * 64 + wr * 32 + mt * 16 + 4 * hi4]);
#pragma unroll
      for (int nt = 0; nt < 2; ++nt)
#pragma unroll
        for (int e = 0; e < 4; ++e)
          accf[mt][nt][e] += sx[e] * (sw[nt] * (float)acci[mt][nt][e]);
    }
  };

  char* S0 = lds_raw;
  char* S1 = lds_raw + 16384;

  stage(S0, 0);
  __syncthreads();                    // drain stage(0) + scale loads
  for (int j = 0; j < NGK; ++j) {
    if (j + 1 < NGK) {
      stage((j & 1) ? S0 : S1, j + 1);
      asm volatile("s_waitcnt vmcnt(4)" ::: "memory");
    } else {
      asm volatile("s_waitcnt vmcnt(0)" ::: "memory");
    }
    __builtin_amdgcn_s_barrier();
    compute((j & 1) ? S1 : S0, j);
    __builtin_amdgcn_s_barrier();
  }

  const int crow0 = bm * 64 + wr * 32 + 4 * hi4;
  const int ccol0 = bn * 64 + wc * 32 + r15;
#pragma unroll
  for (int mt = 0; mt < 2; ++mt)
#pragma unroll
    for (int nt = 0; nt < 2; ++nt)
#pragma unroll
      for (int r = 0; r < 4; ++r) {
        int row = crow0 + mt * 16 + r;
        int col = ccol0 + nt * 16;
        C[(size_t)row * DIM + col] = accf[mt][nt][r];
      }
}

__global__ __launch_bounds__(256, 4) void gemm_kernel(
    const int8_t* __restrict__ Aq, const int8_t* __restrict__ Bq,
    const float* __restrict__ ssxT, const float* __restrict__ sswT,
    float* __restrict__ C) {
  __shared__ char lds_raw[2 * 16384 + 8192];   // 40 KB
  gemm_tile(blockIdx.x, Aq, Bq, ssxT, sswT, C, lds_raw, threadIdx.x);
}

// ---------------- fused cooperative kernel (512 blocks, 2 tiles each) -------

__global__ __launch_bounds__(256, 4) void fused_kernel(
    const float* __restrict__ x, const float* __restrict__ w,
    int8_t* __restrict__ q8, float* __restrict__ ssxT,
    float* __restrict__ sswT, float* __restrict__ C) {
  __shared__ char lds_raw[2 * 16384 + 8192];   // 40 KB

  const int tid  = threadIdx.x;
  const int lane = tid & 63;
  const int wid  = tid >> 6;
  const int l    = lane & 31;

  // phase 1: 128 groups per block (rolled loop — R13 lesson: no full unroll)
  for (int it = 0; it < 16; ++it) {
    const int g = blockIdx.x * 128 + it * 8 + wid * 2 + (lane >> 5);
    quant_group(g, x, w, q8, ssxT, sswT, l);
  }

  cg::this_grid().sync();             // all quant writes visible device-wide

  // phase 2: two GEMM tiles per block
  const int8_t* Aq = q8;
  const int8_t* Bq = q8 + (size_t)TOKENS * DIM;
  gemm_tile(blockIdx.x,       Aq, Bq, ssxT, sswT, C, lds_raw, tid);
  __syncthreads();                    // tile-1 fully done before LDS reuse
  gemm_tile(blockIdx.x + 512, Aq, Bq, ssxT, sswT, C, lds_raw, tid);
}

// ---------------- launch ----------------

extern "C" void kernel_launch(void* const* d_in, const int* in_sizes, int n_in,
                              void* d_out, int out_size, void* d_ws,
                              size_t ws_size, hipStream_t stream) {
  const float* x = (const float*)d_in[0];
  const float* w = (const float*)d_in[1];
  float* out = (float*)d_out;

  int8_t* qx   = (int8_t*)d_ws;                            // 8 MB (qx ++ qw)
  float*  ssxT = (float*)(qx + 2 * (size_t)TOKENS * DIM);  // 128 KB
  float*  sswT = ssxT + NGK * 2048;                        // 128 KB

  void* args[] = {(void*)&x, (void*)&w, (void*)&qx,
                  (void*)&ssxT, (void*)&sswT, (void*)&out};
  hipError_t e = hipLaunchCooperativeKernel(
      (const void*)fused_kernel, dim3(512), dim3(256), args, 0, stream);
  if (e != hipSuccess) {
    (void)hipGetLastError();          // clear sticky error, use R17 path
    const int ngroups = 2 * TOKENS * DIM / GROUP;   // 65536
    quant2_kernel<<<ngroups / 8, 256, 0, stream>>>(x, w, qx, ssxT, sswT);
    gemm_kernel<<<1024, 256, 0, stream>>>(
        qx, qx + (size_t)TOKENS * DIM, ssxT, sswT, out);
  }
}

// Round 22
// 31.421 us; speedup vs baseline: 2.9652x; 2.9652x over previous
//
#include <hip/hip_runtime.h>
#include <hip/hip_fp16.h>
#include <stdint.h>

#define TOKENS 2048
#define DIM    2048
#define GROUP  128
#define NGK    16   // K-groups per row

typedef __attribute__((ext_vector_type(4)))  int   i32x4;
typedef __attribute__((ext_vector_type(4)))  float f32x4;

// ---------------- quantization (int8 q/4 + per-group scale*4) ----------------
// R15 kernel (proven): one-pass variance + wave-uniform outlier fast path.

__device__ __forceinline__ float nearest_q4(float u) {
  float qi = fminf(fmaxf(rintf(u), -7.f), 7.f);
  float a = fabsf(u);
  float m = a <= 14.f ? 12.f : a <= 20.f ? 16.f : a <= 28.f ? 24.f
          : a <= 40.f ? 32.f : a <= 56.f ? 48.f : a <= 80.f ? 64.f : 96.f;
  float qo = copysignf(m, u);
  return (fabsf(u - qo) < fabsf(u - qi)) ? qo : qi;   // int grid wins ties
}

__global__ __launch_bounds__(256) void quant2_kernel(
    const float* __restrict__ x, const float* __restrict__ w,
    int8_t* __restrict__ q8,          // qx (4MB) ++ qw (4MB), values = grid/4
    float* __restrict__ ssxT,         // [16][2048]  scale*4, transposed
    float* __restrict__ sswT) {       // [16][2048]
  const int wid  = threadIdx.x >> 6;
  const int lane = threadIdx.x & 63;
  const int l    = lane & 31;
  const int g    = blockIdx.x * 8 + wid * 2 + (lane >> 5);
  const int NG1  = TOKENS * DIM / GROUP;   // 32768

  const float alpha = (g < NG1) ? 0.9f : 1.0f;
  const float* src  = (g < NG1) ? x : w;
  const int grow    = (g < NG1) ? g : g - NG1;
  const size_t sbase = (size_t)grow * GROUP + l * 4;

  const float4 v = *reinterpret_cast<const float4*>(src + sbase);

  float s  = (v.x + v.y) + (v.z + v.w);
  float ss = fmaf(v.x, v.x, fmaf(v.y, v.y, fmaf(v.z, v.z, v.w * v.w)));
#pragma unroll
  for (int off = 16; off > 0; off >>= 1) {
    s  += __shfl_xor(s,  off, 64);
    ss += __shfl_xor(ss, off, 64);
  }
  const float mean = s * (1.0f / 128.0f);
  const float var  = fmaf(-mean, s, ss) * (1.0f / 127.0f);
  const float scale = fmaf(3.0f, sqrtf(var), fabsf(mean)) * (alpha / 28.0f);
  const float rs4 = 0.25f / scale;

  const float u0 = v.x * rs4, u1 = v.y * rs4, u2 = v.z * rs4, u3 = v.w * rs4;
  const float amax = fmaxf(fmaxf(fabsf(u0), fabsf(u1)),
                           fmaxf(fabsf(u2), fabsf(u3)));

  int i0, i1, i2, i3;
  if (__any(amax >= 9.5f)) {
    float q0 = nearest_q4(u0);
    float q1 = nearest_q4(u1);
    float q2 = nearest_q4(u2);
    float q3 = nearest_q4(u3);
    if (fabsf(q0) > 8.0f)      q1 = 0.0f;
    else if (fabsf(q1) > 8.0f) q0 = 0.0f;
    if (fabsf(q2) > 8.0f)      q3 = 0.0f;
    else if (fabsf(q3) > 8.0f) q2 = 0.0f;
    i0 = (int)q0; i1 = (int)q1; i2 = (int)q2; i3 = (int)q3;
  } else {
    i0 = (int)fminf(fmaxf(rintf(u0), -7.f), 7.f);
    i1 = (int)fminf(fmaxf(rintf(u1), -7.f), 7.f);
    i2 = (int)fminf(fmaxf(rintf(u2), -7.f), 7.f);
    i3 = (int)fminf(fmaxf(rintf(u3), -7.f), 7.f);
  }

  const int p = (i0 & 255) | ((i1 & 255) << 8) |
                ((i2 & 255) << 16) | ((i3 & 255) << 24);
  reinterpret_cast<int*>(q8)[(size_t)g * 32 + l] = p;

  if (l == 0) {
    const float ssc = 4.0f * scale;
    if (g < NG1) ssxT[(grow & 15) * 2048 + (grow >> 4)] = ssc;
    else         sswT[(grow & 15) * 2048 + (grow >> 4)] = ssc;
  }
}

// ---------------- GEMM: C = sum_g ssx*ssw*(int8 group dot) ----------------
// EXACT R17 kernel (session best: 31.63 us). BM=BN=64, grid 1024 = 4
// blocks/CU = 16 waves/CU; mfma_i32_16x16x64_i8; 4 waves (wr,wc) 2x2, wave
// tile 32x32; ratio 1.0 (8 ds_read_b128 : 8 MFMA / group). 2-deep pipeline,
// counted vmcnt(4); XOR swizzle ((row&7)<<4) both-sides; XCD 8x16 chunks.
// Post-R21 status: schedule/geometry/fusion lever space exhausted —
// occupancy (this kernel) was the one win; B-to-reg, split-K, one-barrier,
// deferred scales, 3-deep, cooperative fusion all neutral or regressions.

__device__ __forceinline__ void gload_lds16(const int8_t* g, char* l) {
  __builtin_amdgcn_global_load_lds(
      (__attribute__((address_space(1))) uint32_t*)g,
      (__attribute__((address_space(3))) uint32_t*)l, 16, 0, 0);
}

__global__ __launch_bounds__(256, 4) void gemm_kernel(
    const int8_t* __restrict__ Aq, const int8_t* __restrict__ Bq,
    const float* __restrict__ ssxT, const float* __restrict__ sswT,
    float* __restrict__ C) {
  // 2 stages x (A 8K + B 8K) = 32 KB, + scales 8 KB = 40 KB -> 4 blocks/CU
  __shared__ char lds_raw[2 * 16384 + 8192];
  float* ssx_l = (float*)(lds_raw + 32768);          // [16][64]
  float* ssw_l = (float*)(lds_raw + 32768 + 4096);   // [16][64]

  const int tid  = threadIdx.x;
  const int lane = tid & 63;
  const int wid  = tid >> 6;       // 0..3
  const int wr   = wid >> 1;       // 0..1 (32 rows)
  const int wc   = wid & 1;        // 0..1 (32 cols)
  const int r15  = lane & 15;
  const int hi4  = lane >> 4;      // 0..3

  // XCD c owns bm in [(c&3)*8,+8), bn in [(c>>2)*16,+16): ~3 MB -> L2
  const int bid = blockIdx.x;
  const int c   = bid & 7;
  const int idx = bid >> 3;                       // 0..127
  const int bm  = ((c & 3) << 3) + (idx >> 4);    // 0..31
  const int bn  = ((c >> 2) << 4) + (idx & 15);   // 0..31

  const int8_t* gA = Aq + (size_t)(bm * 64) * DIM;
  const int8_t* gB = Bq + (size_t)(bn * 64) * DIM;

  auto stage = [&](char* buf, int g) {
#pragma unroll
    for (int i = 0; i < 2; ++i) {     // A: 64x128 i8 = 8 KB
      int P   = (i * 256 + tid) * 16;
      int row = P >> 7;
      int cb  = (P & 127) ^ ((row & 7) << 4);
      gload_lds16(gA + (size_t)row * DIM + g * 128 + cb, buf + P);
    }
#pragma unroll
    for (int i = 0; i < 2; ++i) {     // B: 64x128 i8 = 8 KB
      int P   = (i * 256 + tid) * 16;
      int row = P >> 7;
      int cb  = (P & 127) ^ ((row & 7) << 4);
      gload_lds16(gB + (size_t)row * DIM + g * 128 + cb, buf + 8192 + P);
    }
  };

  // ---- stage scale tables, then full drain (keeps manual vmcnt exact) ----
  {                                   // ssx: 1024 floats, 4/thread
    int f = tid * 4;                  // gk = f>>6, r = f&63
    *reinterpret_cast<f32x4*>(&ssx_l[f]) =
        *reinterpret_cast<const f32x4*>(&ssxT[(f >> 6) * 2048 + bm * 64 + (f & 63)]);
  }
  {                                   // ssw: 1024 floats
    int f = tid * 4;
    *reinterpret_cast<f32x4*>(&ssw_l[f]) =
        *reinterpret_cast<const f32x4*>(&sswT[(f >> 6) * 2048 + bn * 64 + (f & 63)]);
  }
  __syncthreads();                    // drain scale loads + publish LDS

  f32x4 accf[2][2] = {};
  const i32x4 zacc = {};

  auto compute = [&](const char* buf, int gk) {
    const char* cA = buf;
    const char* cB = buf + 8192;
    i32x4 acci[2][2];
#pragma unroll
    for (int kh = 0; kh < 2; ++kh) {            // two K=64 halves
      const int kb = kh * 64 + hi4 * 16;        // per-lane k-byte offset
      i32x4 af[2], bf[2];
#pragma unroll
      for (int mt = 0; mt < 2; ++mt) {
        int row = wr * 32 + mt * 16 + r15;
        int pc  = kb ^ ((row & 7) << 4);
        af[mt] = *reinterpret_cast<const i32x4*>(cA + (row << 7) + pc);
      }
#pragma unroll
      for (int nt = 0; nt < 2; ++nt) {
        int row = wc * 32 + nt * 16 + r15;
        int pc  = kb ^ ((row & 7) << 4);
        bf[nt] = *reinterpret_cast<const i32x4*>(cB + (row << 7) + pc);
      }
      __builtin_amdgcn_s_setprio(1);
#pragma unroll
      for (int mt = 0; mt < 2; ++mt)
#pragma unroll
        for (int nt = 0; nt < 2; ++nt)
          acci[mt][nt] = __builtin_amdgcn_mfma_i32_16x16x64_i8(
              af[mt], bf[nt], kh == 0 ? zacc : acci[mt][nt], 0, 0, 0);
      __builtin_amdgcn_s_setprio(0);
    }
    // accf += ssx[row] * ssw[col] * float(acci)
    float sw[2];
#pragma unroll
    for (int nt = 0; nt < 2; ++nt)
      sw[nt] = ssw_l[gk * 64 + wc * 32 + nt * 16 + r15];
#pragma unroll
    for (int mt = 0; mt < 2; ++mt) {
      f32x4 sx = *reinterpret_cast<const f32x4*>(
          &ssx_l[gk * 64 + wr * 32 + mt * 16 + 4 * hi4]);
#pragma unroll
      for (int nt = 0; nt < 2; ++nt)
#pragma unroll
        for (int e = 0; e < 4; ++e)
          accf[mt][nt][e] += sx[e] * (sw[nt] * (float)acci[mt][nt][e]);
    }
  };

  char* S0 = lds_raw;
  char* S1 = lds_raw + 16384;

  stage(S0, 0);
  for (int j = 0; j < NGK; ++j) {     // 16 K-groups
    if (j + 1 < NGK) {
      stage((j & 1) ? S0 : S1, j + 1);
      asm volatile("s_waitcnt vmcnt(4)" ::: "memory");   // group j's loads done
    } else {
      asm volatile("s_waitcnt vmcnt(0)" ::: "memory");
    }
    __builtin_amdgcn_s_barrier();
    compute((j & 1) ? S1 : S0, j);
    __builtin_amdgcn_s_barrier();
  }

  // ---- direct C write ----
  // C/D 16x16: col = lane&15, row = (lane>>4)*4 + reg
  const int crow0 = bm * 64 + wr * 32 + 4 * hi4;
  const int ccol0 = bn * 64 + wc * 32 + r15;
#pragma unroll
  for (int mt = 0; mt < 2; ++mt)
#pragma unroll
    for (int nt = 0; nt < 2; ++nt)
#pragma unroll
      for (int r = 0; r < 4; ++r) {
        int row = crow0 + mt * 16 + r;
        int col = ccol0 + nt * 16;
        C[(size_t)row * DIM + col] = accf[mt][nt][r];
      }
}

// ---------------- launch ----------------

extern "C" void kernel_launch(void* const* d_in, const int* in_sizes, int n_in,
                              void* d_out, int out_size, void* d_ws,
                              size_t ws_size, hipStream_t stream) {
  const float* x = (const float*)d_in[0];
  const float* w = (const float*)d_in[1];
  float* out = (float*)d_out;

  int8_t* qx   = (int8_t*)d_ws;                         // 4 MB
  int8_t* qw   = qx + (size_t)TOKENS * DIM;             // 4 MB
  float*  ssxT = (float*)(qw + (size_t)DIM * DIM);      // 128 KB
  float*  sswT = ssxT + NGK * 2048;                     // 128 KB

  const int ngroups = 2 * TOKENS * DIM / GROUP;         // 65536
  quant2_kernel<<<ngroups / 8, 256, 0, stream>>>(x, w, qx, ssxT, sswT);

  gemm_kernel<<<1024, 256, 0, stream>>>(qx, qw, ssxT, sswT, out);
}